// Round 17
// baseline (198.223 us; speedup 1.0000x reference)
//
#include <hip/hip_runtime.h>
#include <stdint.h>

typedef unsigned short u16;
typedef __bf16 bf16x8 __attribute__((ext_vector_type(8)));
typedef short s16x8 __attribute__((ext_vector_type(8)));
typedef float f32x4 __attribute__((ext_vector_type(4)));

union FragU { s16x8 s; bf16x8 b; uint4 u; };

__device__ __forceinline__ f32x4 mfma_bf16(s16x8 a, s16x8 b, f32x4 c) {
    FragU ua, ub; ua.s = a; ub.s = b;
    return __builtin_amdgcn_mfma_f32_16x16x32_bf16(ua.b, ub.b, c, 0, 0, 0);
}

__device__ __forceinline__ u16 f2bf(float f) {
    uint32_t u = __float_as_uint(f);
    u += 0x7fffu + ((u >> 16) & 1u);   // RNE
    return (u16)(u >> 16);
}

__device__ __forceinline__ float bf2f(u16 u) {
    return __uint_as_float((uint32_t)u << 16);
}

__device__ __forceinline__ void gload_lds16(const void* g, void* l) {
    __builtin_amdgcn_global_load_lds((__attribute__((address_space(1))) void*)g,
                                     (__attribute__((address_space(3))) void*)l,
                                     16, 0, 0);
}

// bijective XCD-aware block swizzle (requires nwg % 8 == 0)
__device__ __forceinline__ void xcd_swz(int& bx, int& by, int& bz) {
    int nx = gridDim.x, ny = gridDim.y;
    int nwg = nx * ny * gridDim.z;
    int lin = blockIdx.x + nx * (blockIdx.y + ny * blockIdx.z);
    int cpx = nwg >> 3;
    int s = (lin & 7) * cpx + (lin >> 3);
    bx = s % nx; s /= nx;
    by = s % ny; bz = s / ny;
}

// ---------------------------------------------------------------- fused cast f32->bf16
__global__ void k_cast_all(
    const float* __restrict__ s0, u16* __restrict__ d0, int n0,
    const float* __restrict__ s1, u16* __restrict__ d1, int n1,
    const float* __restrict__ s2, u16* __restrict__ d2, int n2,
    const float* __restrict__ s3, u16* __restrict__ d3, int n3,
    const float* __restrict__ s4, u16* __restrict__ d4, int n4_,
    const float* __restrict__ s5, u16* __restrict__ d5, int n5)
{
    const float* src; u16* dst; int n4;
    switch (blockIdx.y) {
        case 0: src = s0; dst = d0; n4 = n0; break;
        case 1: src = s1; dst = d1; n4 = n1; break;
        case 2: src = s2; dst = d2; n4 = n2; break;
        case 3: src = s3; dst = d3; n4 = n3; break;
        case 4: src = s4; dst = d4; n4 = n4_; break;
        default: src = s5; dst = d5; n4 = n5; break;
    }
    int i = blockIdx.x * blockDim.x + threadIdx.x;
    int stride = gridDim.x * blockDim.x;
    for (; i < n4; i += stride) {
        float4 v = ((const float4*)src)[i];
        u16 us[4] = {f2bf(v.x), f2bf(v.y), f2bf(v.z), f2bf(v.w)};
        *(uint2*)(dst + (size_t)i * 4) = *(uint2*)us;
    }
}

// ---------------------------------------------------------------- GEMM C = A * W^T (+ bias)
// BK=32 DOUBLE-buffered counted-vmcnt pipeline at the SAME 32KB LDS as the 2-barrier
// version -> 4 blocks/CU retained (R6/R15's dbuf regressions were the 64KB occupancy
// halving, not the pipeline mechanism, which R11 validated in flash).
// Per K-step: issue stage(t+1) into buf^1 (4 gloads) -> vmcnt(4) (waits only the 4
// oldest = stage(t)) -> s_barrier -> 16 MFMA -> s_barrier. No vmcnt(0) in the loop.
// Swizzle (BK=32): 4 slots/row; source pre-XOR (tid&3)^(srow&3); read slot (g^(cc&3)).
// OUTMODE 0: f32+bias; 1: bf16+bias; 2: bf16 partial no bias;
// 3: bf16+bias TRANSPOSED V store into Vt[((b*16+h)*64+dh)*2048 + s].
template<int RELU, int OUTMODE>
__device__ __forceinline__ void gemm_body(
    u16* __restrict__ AsB, u16* __restrict__ BsB,   // base of [2][128*32] u16 buffers
    const u16* __restrict__ A, const u16* __restrict__ W,
    const float* __restrict__ bias, void* __restrict__ Cout,
    int M, int N, int K, int row0, int col0, int kbeg, int kend)
{
    const int tid  = threadIdx.x;
    const int wid  = tid >> 6;
    const int lane = tid & 63;
    const int g    = lane >> 4;     // 0..3
    const int cc   = lane & 15;     // 0..15
    const int wr   = wid >> 1;      // wave row 0..1
    const int wc   = wid & 1;       // wave col 0..1

    f32x4 zero = {0.f, 0.f, 0.f, 0.f};
    f32x4 acc[4][4];
#pragma unroll
    for (int i = 0; i < 4; i++)
#pragma unroll
        for (int j = 0; j < 4; j++) acc[i][j] = zero;

    // staging: 2 gloads for A (rows srow, srow+64) + 2 for B; source col pre-XOR'd
    const int srow = tid >> 2;                         // 0..63
    const int scol = ((tid & 3) ^ (srow & 3)) * 8;     // u16 offset
    const u16* gA0 = A + (size_t)(row0 + srow) * K + scol;
    const u16* gB0 = W + (size_t)(col0 + srow) * K + scol;
    // wave-uniform LDS dest: wave w, gload j -> rows j*64 + w*16.. : off = j*2048 + w*512
    const int ldOff = wid * 512;

    const int xm = (cc & 3);     // XOR key for frag reads (row&3 == cc&3)

    auto stage = [&](int buf, int k0) {
        u16* lA = AsB + buf * 4096 + ldOff;
        u16* lB = BsB + buf * 4096 + ldOff;
        gload_lds16(gA0 + k0,                  lA);
        gload_lds16(gA0 + (size_t)64 * K + k0, lA + 2048);
        gload_lds16(gB0 + k0,                  lB);
        gload_lds16(gB0 + (size_t)64 * K + k0, lB + 2048);
    };

    const int nsteps = (kend - kbeg) >> 5;
    stage(0, kbeg);
    __builtin_amdgcn_sched_barrier(0);

    for (int step = 0; step < nsteps; ++step) {
        const int cur = step & 1;
        if (step + 1 < nsteps) {
            stage(cur ^ 1, kbeg + (step + 1) * 32);
            __builtin_amdgcn_sched_barrier(0);
            asm volatile("s_waitcnt vmcnt(4)" ::: "memory");   // stage(t)'s 4 landed
        } else {
            asm volatile("s_waitcnt vmcnt(0)" ::: "memory");   // tail
        }
        __builtin_amdgcn_s_barrier();                          // all waves' stage(t) done
        __builtin_amdgcn_sched_barrier(0);

        const u16* Asc = AsB + cur * 4096;
        const u16* Bsc = BsB + cur * 4096;
        const int slot = (g ^ xm) * 8;
        s16x8 af[4], bf[4];
#pragma unroll
        for (int mi = 0; mi < 4; mi++)
            af[mi] = *(const s16x8*)&Asc[(wr * 64 + mi * 16 + cc) * 32 + slot];
#pragma unroll
        for (int ni = 0; ni < 4; ni++)
            bf[ni] = *(const s16x8*)&Bsc[(wc * 64 + ni * 16 + cc) * 32 + slot];
        __builtin_amdgcn_s_setprio(1);
#pragma unroll
        for (int mi = 0; mi < 4; mi++)
#pragma unroll
            for (int ni = 0; ni < 4; ni++)
                acc[mi][ni] = mfma_bf16(af[mi], bf[ni], acc[mi][ni]);
        __builtin_amdgcn_s_setprio(0);

        __builtin_amdgcn_sched_barrier(0);
        __builtin_amdgcn_s_barrier();      // reads of buf done before t+2 overwrites it
        __builtin_amdgcn_sched_barrier(0);
    }

#pragma unroll
    for (int ni = 0; ni < 4; ni++) {
        int col = col0 + wc * 64 + ni * 16 + cc;
        float bvv = 0.f;
        if (OUTMODE != 2) bvv = bias[col];
        if (OUTMODE == 3) {
            int head = col >> 6, dh = col & 63;
#pragma unroll
            for (int mi = 0; mi < 4; mi++) {
                int row = row0 + wr * 64 + mi * 16 + g * 4;     // s global
                int bb = row >> 11, sl = row & 2047;
                u16 us[4];
#pragma unroll
                for (int r = 0; r < 4; r++) us[r] = f2bf(acc[mi][ni][r] + bvv);
                *(uint2*)&((u16*)Cout)[(((size_t)(bb * 16 + head) * 64 + dh) << 11) + sl]
                    = *(uint2*)us;
            }
        } else {
#pragma unroll
            for (int mi = 0; mi < 4; mi++) {
                int row = row0 + wr * 64 + mi * 16 + g * 4;
#pragma unroll
                for (int r = 0; r < 4; r++) {
                    float v = acc[mi][ni][r] + bvv;
                    if (RELU) v = fmaxf(v, 0.f);
                    size_t idx = (size_t)(row + r) * N + col;
                    if (OUTMODE == 0) ((float*)Cout)[idx] = v;
                    else              ((u16*)Cout)[idx] = f2bf(v);
                }
            }
        }
    }
}

#define GEMM_LDS_DECL \
    __shared__ __align__(16) u16 As[2][128 * 32]; \
    __shared__ __align__(16) u16 Bs[2][128 * 32];

// Q, K, V projections in ONE launch: z=0 -> Q, z=1 -> K, z=2 -> V transposed into Vt.
__global__ __launch_bounds__(256, 4) void k_gemm_qkv(
    const u16* __restrict__ A, const u16* __restrict__ Wq, const u16* __restrict__ Wk,
    const u16* __restrict__ Wv, const float* __restrict__ bq, const float* __restrict__ bk,
    const float* __restrict__ bv, u16* __restrict__ Q, u16* __restrict__ K,
    u16* __restrict__ Vt, int M, int N, int Kd)
{
    GEMM_LDS_DECL
    int bx, by, bz; xcd_swz(bx, by, bz);
    if (bz == 0)
        gemm_body<0, 1>(&As[0][0], &Bs[0][0], A, Wq, bq, Q,  M, N, Kd, by * 128, bx * 128, 0, Kd);
    else if (bz == 1)
        gemm_body<0, 1>(&As[0][0], &Bs[0][0], A, Wk, bk, K,  M, N, Kd, by * 128, bx * 128, 0, Kd);
    else
        gemm_body<0, 3>(&As[0][0], &Bs[0][0], A, Wv, bv, Vt, M, N, Kd, by * 128, bx * 128, 0, Kd);
}

__global__ __launch_bounds__(256, 4) void k_gemm_relu_bf16(
    const u16* __restrict__ A, const u16* __restrict__ W, const float* __restrict__ bias,
    u16* __restrict__ C, int M, int N, int K)
{
    GEMM_LDS_DECL
    int bx, by, bz; xcd_swz(bx, by, bz);
    gemm_body<1, 1>(&As[0][0], &Bs[0][0], A, W, bias, C, M, N, K, by * 128, bx * 128, 0, K);
}

// FFN2 split-K partials: gridDim.z = 4, each covers K-range [bz*1024, +1024), bf16 out, no bias.
__global__ __launch_bounds__(256, 4) void k_gemm_part(
    const u16* __restrict__ A, const u16* __restrict__ W,
    u16* __restrict__ p0, u16* __restrict__ p1, u16* __restrict__ p2, u16* __restrict__ p3,
    int M, int N, int K)
{
    GEMM_LDS_DECL
    int bx, by, bz; xcd_swz(bx, by, bz);
    u16* out = (bz == 0) ? p0 : (bz == 1) ? p1 : (bz == 2) ? p2 : p3;
    gemm_body<0, 2>(&As[0][0], &Bs[0][0], A, W, nullptr, out, M, N, K, by * 128, bx * 128,
                    bz * 1024, bz * 1024 + 1024);
}

// ---------------------------------------------------------------- flash attention
// R16-PROVEN: 512 thr (8 waves), KVB=128, swapped QK^T, fixed-shift softmax (shift in
// MFMA C-init), K dbuf with T4 counted-vmcnt, V reg-staged, bf16 out, XCD swizzle.
__global__ __launch_bounds__(512, 4) void k_flash(
    const u16* __restrict__ Q, const u16* __restrict__ Kb,
    const u16* __restrict__ Vt, u16* __restrict__ O)
{
    constexpr int S = 2048, Dm = 1024, H = 16;
    constexpr int KVB = 128, NT = S / KVB;
    constexpr float qsc = 0.125f * 1.44269504f;  // 1/sqrt(64) * log2(e)
    int bx, by, bz; xcd_swz(bx, by, bz);
    int qt = bx, h = by, b = bz;
    int tid = threadIdx.x, wid = tid >> 6, lane = tid & 63;
    int g = lane >> 4, cc = lane & 15;

    __shared__ __align__(16) u16 Ks[2][128 * 64];   // [kv][d], slot ^= (kv&7)
    __shared__ __align__(16) u16 Vs[64 * 128];      // [d][sigma(kv)], idx ^= (d&7)<<3

    int q0 = qt * 128 + wid * 16;
    size_t base = (size_t)b * S * Dm + h * 64;

    FragU uq0, uq1, qs0, qs1;
    uq0.s = *(const s16x8*)(Q + base + (size_t)(q0 + cc) * Dm + g * 8);
    uq1.s = *(const s16x8*)(Q + base + (size_t)(q0 + cc) * Dm + 32 + g * 8);
#pragma unroll
    for (int e = 0; e < 8; e++) {
        qs0.b[e] = (__bf16)((float)uq0.b[e] * qsc);
        qs1.b[e] = (__bf16)((float)uq1.b[e] * qsc);
    }
    s16x8 qf0 = qs0.s, qf1 = qs1.s;

    f32x4 minit = {-8.f, -8.f, -8.f, -8.f};
    f32x4 zero = {0.f, 0.f, 0.f, 0.f};
    f32x4 o[4];
#pragma unroll
    for (int t = 0; t < 4; t++) o[t] = zero;
    f32x4 lacc = zero;

    const int krow = tid >> 3;                         // 0..63
    const int kcol = ((tid & 7) ^ (krow & 7)) * 8;
    const u16* kSrcBase = Kb + base + (size_t)krow * Dm + kcol;
    const int kOff = wid * 512;

    const int vrow = tid >> 3;                         // 0..63 (d)
    const int vch  = (tid & 7) * 8;
    const int xmv  = (vrow & 7) << 3;
    const int cb0  = ((vch >> 5) << 5) | (((vch >> 4) & 1) << 2) | (((vch >> 2) & 3) << 3);
    const int cb1  = cb0 + 64;
    const u16* vSrcBase = Vt + (size_t)(b * H + h) * 64 * S + (size_t)vrow * S;
    u16* vq0a = &Vs[(vrow * 128 + cb0) ^ xmv];
    u16* vq0b = &Vs[(vrow * 128 + cb0 + 8) ^ xmv];
    u16* vq1a = &Vs[(vrow * 128 + cb1) ^ xmv];
    u16* vq1b = &Vs[(vrow * 128 + cb1 + 8) ^ xmv];

    const int xm = cc & 7;

    gload_lds16(kSrcBase,                   &Ks[0][kOff]);
    gload_lds16(kSrcBase + (size_t)64 * Dm, &Ks[0][kOff + 4096]);
    __builtin_amdgcn_sched_barrier(0);
    s16x8 vpre0 = *(const s16x8*)(vSrcBase + vch);
    s16x8 vpre1 = *(const s16x8*)(vSrcBase + 64 + vch);
    __builtin_amdgcn_sched_barrier(0);

    for (int it = 0; it < NT; ++it) {
        const int cur = it & 1;
        const int kv0 = it * KVB;

        asm volatile("s_waitcnt vmcnt(2)" ::: "memory");
        __builtin_amdgcn_s_barrier();
        __builtin_amdgcn_sched_barrier(0);

        {
            FragU a0, a1; a0.s = vpre0; a1.s = vpre1;
            *(uint2*)vq0a = make_uint2(a0.u.x, a0.u.y);
            *(uint2*)vq0b = make_uint2(a0.u.z, a0.u.w);
            *(uint2*)vq1a = make_uint2(a1.u.x, a1.u.y);
            *(uint2*)vq1b = make_uint2(a1.u.z, a1.u.w);
        }
        __builtin_amdgcn_sched_barrier(0);
        if (it + 1 < NT) {
            gload_lds16(kSrcBase + (size_t)(kv0 + KVB) * Dm,      &Ks[cur ^ 1][kOff]);
            gload_lds16(kSrcBase + (size_t)(kv0 + KVB + 64) * Dm, &Ks[cur ^ 1][kOff + 4096]);
        }
        __builtin_amdgcn_sched_barrier(0);
        asm volatile("s_waitcnt lgkmcnt(0)" ::: "memory");
        __builtin_amdgcn_s_barrier();
        __builtin_amdgcn_sched_barrier(0);

        const u16* Kc = Ks[cur];
        f32x4 sacc[8];
#pragma unroll
        for (int t = 0; t < 8; t++) sacc[t] = minit;
        __builtin_amdgcn_s_setprio(1);
#pragma unroll
        for (int t = 0; t < 8; t++) {
            const u16* kr = &Kc[(t * 16 + cc) * 64];
            s16x8 kf0 = *(const s16x8*)(kr + ((0 + g) ^ xm) * 8);
            s16x8 kf1 = *(const s16x8*)(kr + ((4 + g) ^ xm) * 8);
            sacc[t] = mfma_bf16(kf0, qf0, sacc[t]);
            sacc[t] = mfma_bf16(kf1, qf1, sacc[t]);
        }
        __builtin_amdgcn_s_setprio(0);

        FragU pb[4];
#pragma unroll
        for (int t = 0; t < 8; t++)
#pragma unroll
            for (int r = 0; r < 4; r++) {
                float pv = __builtin_amdgcn_exp2f(sacc[t][r]);
                lacc[r] += pv;
                pb[t >> 1].b[(t & 1) * 4 + r] = (__bf16)pv;
            }

        __builtin_amdgcn_s_setprio(1);
#pragma unroll
        for (int td = 0; td < 4; td++) {
            const int rb = (td * 16 + cc) * 128;
#pragma unroll
            for (int kk = 0; kk < 4; kk++) {
                s16x8 vf = *(const s16x8*)&Vs[(rb + kk * 32 + g * 8) ^ (xm << 3)];
                o[td] = mfma_bf16(vf, pb[kk].s, o[td]);
            }
        }
        __builtin_amdgcn_s_setprio(0);

        if (it + 1 < NT) {
            vpre0 = *(const s16x8*)(vSrcBase + kv0 + KVB + vch);
            vpre1 = *(const s16x8*)(vSrcBase + kv0 + KVB + 64 + vch);
        }
        __builtin_amdgcn_sched_barrier(0);
    }

    float l_run = (lacc[0] + lacc[1]) + (lacc[2] + lacc[3]);
    l_run += __shfl_xor(l_run, 16, 64);
    l_run += __shfl_xor(l_run, 32, 64);
    float inv = 1.f / l_run;
#pragma unroll
    for (int td = 0; td < 4; td++) {
        u16 us[4] = {f2bf(o[td][0] * inv), f2bf(o[td][1] * inv),
                     f2bf(o[td][2] * inv), f2bf(o[td][3] * inv)};
        *(uint2*)&O[(size_t)(b * S + q0 + cc) * Dm + h * 64 + td * 16 + g * 4] = *(uint2*)us;
    }
}

// ---------------------------------------------------------------- residual + LN1 -> bf16 h only
__global__ __launch_bounds__(256) void k_ln1(
    const float* __restrict__ A, const u16* __restrict__ B,
    const float* __restrict__ gw, const float* __restrict__ bw,
    u16* __restrict__ outb)
{
    constexpr int D = 1024;
    int row = blockIdx.x;
    int t = threadIdx.x;
    int lane = t & 63, wid = t >> 6;
    size_t idx = (size_t)row * D + t * 4;
    float4 va = ((const float4*)(A + (size_t)row * D))[t];
    uint2 vb = *(const uint2*)(B + idx);
    float v0 = va.x + bf2f((u16)vb.x);
    float v1 = va.y + bf2f((u16)(vb.x >> 16));
    float v2 = va.z + bf2f((u16)vb.y);
    float v3 = va.w + bf2f((u16)(vb.y >> 16));
    float sum = v0 + v1 + v2 + v3;
    float sq  = v0 * v0 + v1 * v1 + v2 * v2 + v3 * v3;
#pragma unroll
    for (int off = 1; off < 64; off <<= 1) {
        sum += __shfl_xor(sum, off, 64);
        sq  += __shfl_xor(sq,  off, 64);
    }
    __shared__ float s1[4], s2[4];
    if (lane == 0) { s1[wid] = sum; s2[wid] = sq; }
    __syncthreads();
    sum = s1[0] + s1[1] + s1[2] + s1[3];
    sq  = s2[0] + s2[1] + s2[2] + s2[3];
    float mu  = sum * (1.f / D);
    float var = sq * (1.f / D) - mu * mu;
    float rs  = rsqrtf(var + 1e-5f);
    float4 gv = ((const float4*)gw)[t];
    float4 bv = ((const float4*)bw)[t];
    u16 us[4] = {f2bf((v0 - mu) * rs * gv.x + bv.x),
                 f2bf((v1 - mu) * rs * gv.y + bv.y),
                 f2bf((v2 - mu) * rs * gv.z + bv.z),
                 f2bf((v3 - mu) * rs * gv.w + bv.w)};
    *(uint2*)(outb + idx) = *(uint2*)us;
}

// ---------------------------------------------------------------- LN2: h(bf16) + (p0..p3+bias) -> LN
__global__ __launch_bounds__(256) void k_ln2(
    const u16* __restrict__ A,
    const u16* __restrict__ p0, const u16* __restrict__ p1,
    const u16* __restrict__ p2, const u16* __restrict__ p3,
    const float* __restrict__ bias,
    const float* __restrict__ gw, const float* __restrict__ bw,
    float* __restrict__ outf)
{
    constexpr int D = 1024;
    int row = blockIdx.x;
    int t = threadIdx.x;
    int lane = t & 63, wid = t >> 6;
    size_t idx = (size_t)row * D + t * 4;
    uint2 ha = *(const uint2*)(A + idx);
    float4 bb = ((const float4*)bias)[t];
    float v0 = bf2f((u16)ha.x)         + bb.x;
    float v1 = bf2f((u16)(ha.x >> 16)) + bb.y;
    float v2 = bf2f((u16)ha.y)         + bb.z;
    float v3 = bf2f((u16)(ha.y >> 16)) + bb.w;
    const u16* ps[4] = {p0, p1, p2, p3};
#pragma unroll
    for (int pi = 0; pi < 4; pi++) {
        uint2 q = *(const uint2*)(ps[pi] + idx);
        v0 += bf2f((u16)q.x);
        v1 += bf2f((u16)(q.x >> 16));
        v2 += bf2f((u16)q.y);
        v3 += bf2f((u16)(q.y >> 16));
    }
    float sum = v0 + v1 + v2 + v3;
    float sq  = v0 * v0 + v1 * v1 + v2 * v2 + v3 * v3;
#pragma unroll
    for (int off = 1; off < 64; off <<= 1) {
        sum += __shfl_xor(sum, off, 64);
        sq  += __shfl_xor(sq,  off, 64);
    }
    __shared__ float s1[4], s2[4];
    if (lane == 0) { s1[wid] = sum; s2[wid] = sq; }
    __syncthreads();
    sum = s1[0] + s1[1] + s1[2] + s1[3];
    sq  = s2[0] + s2[1] + s2[2] + s2[3];
    float mu  = sum * (1.f / D);
    float var = sq * (1.f / D) - mu * mu;
    float rs  = rsqrtf(var + 1e-5f);
    float4 gv = ((const float4*)gw)[t];
    float4 bv = ((const float4*)bw)[t];
    float4 yo = {(v0 - mu) * rs * gv.x + bv.x,
                 (v1 - mu) * rs * gv.y + bv.y,
                 (v2 - mu) * rs * gv.z + bv.z,
                 (v3 - mu) * rs * gv.w + bv.w};
    ((float4*)(outf + (size_t)row * D))[t] = yo;
}

// ---------------------------------------------------------------- launch
extern "C" void kernel_launch(void* const* d_in, const int* in_sizes, int n_in,
                              void* d_out, int out_size, void* d_ws, size_t ws_size,
                              hipStream_t stream)
{
    constexpr int B = 2, S = 2048, D = 1024, F = 4096, H = 16;
    constexpr int M = B * S;
    const float* x   = (const float*)d_in[0];
    const float* Wq  = (const float*)d_in[1];
    const float* bq  = (const float*)d_in[2];
    const float* Wk  = (const float*)d_in[3];
    const float* bk  = (const float*)d_in[4];
    const float* Wv  = (const float*)d_in[5];
    const float* bv  = (const float*)d_in[6];
    const float* W1  = (const float*)d_in[7];
    const float* b1  = (const float*)d_in[8];
    const float* W2  = (const float*)d_in[9];
    const float* b2  = (const float*)d_in[10];
    const float* g1  = (const float*)d_in[11];
    const float* be1 = (const float*)d_in[12];
    const float* g2  = (const float*)d_in[13];
    const float* be2 = (const float*)d_in[14];
    float* out = (float*)d_out;

    char* ws = (char*)d_ws;
    size_t off = 0;
    auto alloc = [&](size_t bytes) {
        void* p = ws + off;
        off += (bytes + 255) & ~(size_t)255;
        return p;
    };
    u16* xb    = (u16*)alloc((size_t)M * D * 2);   // dead after QKV -> p0
    u16* wqb   = (u16*)alloc((size_t)D * D * 2);
    u16* wkb   = (u16*)alloc((size_t)D * D * 2);
    u16* wvb   = (u16*)alloc((size_t)D * D * 2);
    u16* w1b   = (u16*)alloc((size_t)F * D * 2);   // dead after FFN1 -> p1
    u16* w2b   = (u16*)alloc((size_t)D * F * 2);
    u16* Qb    = (u16*)alloc((size_t)M * D * 2);   // dead after flash -> p3
    u16* Kbf   = (u16*)alloc((size_t)M * D * 2);
    u16* Vtb   = (u16*)alloc((size_t)M * D * 2);
    u16* ffn1  = (u16*)alloc((size_t)M * F * 2);   // dedicated: must NOT alias p0..p3
    u16* attnb = (u16*)alloc((size_t)M * D * 2);   // bf16 attn; dead after LN1 -> p2
    u16* hb    = (u16*)alloc((size_t)M * D * 2);
    u16* p0 = xb;
    u16* p1 = w1b;
    u16* p2 = attnb;
    u16* p3 = Qb;

    dim3 blk(256);
    k_cast_all<<<dim3(128, 6), blk, 0, stream>>>(
        x,  xb,  M * D / 4,
        Wq, wqb, D * D / 4,
        Wk, wkb, D * D / 4,
        Wv, wvb, D * D / 4,
        W1, w1b, F * D / 4,
        W2, w2b, D * F / 4);

    k_gemm_qkv<<<dim3(D / 128, M / 128, 3), blk, 0, stream>>>(
        xb, wqb, wkb, wvb, bq, bk, bv, Qb, Kbf, Vtb, M, D, D);
    k_flash<<<dim3(S / 128, H, B), dim3(512), 0, stream>>>(Qb, Kbf, Vtb, attnb);
    k_ln1<<<dim3(M), blk, 0, stream>>>(x, attnb, g1, be1, hb);
    k_gemm_relu_bf16<<<dim3(F / 128, M / 128), blk, 0, stream>>>(hb, w1b, b1, ffn1, M, F, D);
    k_gemm_part<<<dim3(D / 128, M / 128, 4), blk, 0, stream>>>(
        ffn1, w2b, p0, p1, p2, p3, M, D, F);
    k_ln2<<<dim3(M), blk, 0, stream>>>(hb, p0, p1, p2, p3, b2, g2, be2, out);
}

// Round 18
// 186.210 us; speedup vs baseline: 1.0645x; 1.0645x over previous
//
#include <hip/hip_runtime.h>
#include <stdint.h>

typedef unsigned short u16;
typedef __bf16 bf16x8 __attribute__((ext_vector_type(8)));
typedef short s16x8 __attribute__((ext_vector_type(8)));
typedef float f32x4 __attribute__((ext_vector_type(4)));

union FragU { s16x8 s; bf16x8 b; uint4 u; };

__device__ __forceinline__ f32x4 mfma_bf16(s16x8 a, s16x8 b, f32x4 c) {
    FragU ua, ub; ua.s = a; ub.s = b;
    return __builtin_amdgcn_mfma_f32_16x16x32_bf16(ua.b, ub.b, c, 0, 0, 0);
}

__device__ __forceinline__ u16 f2bf(float f) {
    uint32_t u = __float_as_uint(f);
    u += 0x7fffu + ((u >> 16) & 1u);   // RNE
    return (u16)(u >> 16);
}

__device__ __forceinline__ float bf2f(u16 u) {
    return __uint_as_float((uint32_t)u << 16);
}

__device__ __forceinline__ void gload_lds16(const void* g, void* l) {
    __builtin_amdgcn_global_load_lds((__attribute__((address_space(1))) void*)g,
                                     (__attribute__((address_space(3))) void*)l,
                                     16, 0, 0);
}

// bijective XCD-aware block swizzle (requires nwg % 8 == 0)
__device__ __forceinline__ void xcd_swz(int& bx, int& by, int& bz) {
    int nx = gridDim.x, ny = gridDim.y;
    int nwg = nx * ny * gridDim.z;
    int lin = blockIdx.x + nx * (blockIdx.y + ny * blockIdx.z);
    int cpx = nwg >> 3;
    int s = (lin & 7) * cpx + (lin >> 3);
    bx = s % nx; s /= nx;
    by = s % ny; bz = s / ny;
}

// ---------------------------------------------------------------- fused cast f32->bf16
__global__ void k_cast_all(
    const float* __restrict__ s0, u16* __restrict__ d0, int n0,
    const float* __restrict__ s1, u16* __restrict__ d1, int n1,
    const float* __restrict__ s2, u16* __restrict__ d2, int n2,
    const float* __restrict__ s3, u16* __restrict__ d3, int n3,
    const float* __restrict__ s4, u16* __restrict__ d4, int n4_,
    const float* __restrict__ s5, u16* __restrict__ d5, int n5)
{
    const float* src; u16* dst; int n4;
    switch (blockIdx.y) {
        case 0: src = s0; dst = d0; n4 = n0; break;
        case 1: src = s1; dst = d1; n4 = n1; break;
        case 2: src = s2; dst = d2; n4 = n2; break;
        case 3: src = s3; dst = d3; n4 = n3; break;
        case 4: src = s4; dst = d4; n4 = n4_; break;
        default: src = s5; dst = d5; n4 = n5; break;
    }
    int i = blockIdx.x * blockDim.x + threadIdx.x;
    int stride = gridDim.x * blockDim.x;
    for (; i < n4; i += stride) {
        float4 v = ((const float4*)src)[i];
        u16 us[4] = {f2bf(v.x), f2bf(v.y), f2bf(v.z), f2bf(v.w)};
        *(uint2*)(dst + (size_t)i * 4) = *(uint2*)us;
    }
}

// ---------------------------------------------------------------- GEMM C = A * W^T (+ bias)
// R16-PROVEN structure (session best, 186.8us): 128x128 tile, BK=64, XOR-swizzled LDS,
// single 32KB buffer shared by all instantiations, 2 barriers/K-step, 4 blocks/CU.
// GEMM-restructure attempts all regressed: R6/R15 (64KB dbuf -> occupancy halved),
// R17 (BK=32 dbuf -> 4.2M bank conflicts + doubled barriers). Do not retry at 128^2.
// OUTMODE 0: f32+bias; 1: bf16+bias; 2: bf16 partial no bias;
// 3: bf16+bias TRANSPOSED V store into Vt[((b*16+h)*64+dh)*2048 + s].
template<int RELU, int OUTMODE>
__device__ __forceinline__ void gemm_body(
    u16* __restrict__ As, u16* __restrict__ Bs,
    const u16* __restrict__ A, const u16* __restrict__ W,
    const float* __restrict__ bias, void* __restrict__ Cout,
    int M, int N, int K, int row0, int col0, int kbeg, int kend)
{
    const int tid  = threadIdx.x;
    const int wid  = tid >> 6;
    const int lane = tid & 63;
    const int g    = lane >> 4;     // 0..3
    const int cc   = lane & 15;     // 0..15
    const int wr   = wid >> 1;      // wave row 0..1
    const int wc   = wid & 1;       // wave col 0..1

    f32x4 zero = {0.f, 0.f, 0.f, 0.f};
    f32x4 acc[4][4];
#pragma unroll
    for (int i = 0; i < 4; i++)
#pragma unroll
        for (int j = 0; j < 4; j++) acc[i][j] = zero;

    const int srow = tid >> 3;                         // 0..31
    const int scol = ((tid & 7) ^ (srow & 7)) * 8;     // u16 offset, pre-XOR'd source
    const u16* gA0 = A + (size_t)(row0 + srow) * K + scol;
    const u16* gB0 = W + (size_t)(col0 + srow) * K + scol;
    u16* lA0 = &As[wid * 512];   // wave-uniform; HW adds lane*16B
    u16* lB0 = &Bs[wid * 512];

    const int xm = (cc & 7);     // XOR key for frag reads

    for (int k0 = kbeg; k0 < kend; k0 += 64) {
#pragma unroll
        for (int j = 0; j < 4; j++)
            gload_lds16(gA0 + (size_t)(j * 32) * K + k0, lA0 + j * 2048);
#pragma unroll
        for (int j = 0; j < 4; j++)
            gload_lds16(gB0 + (size_t)(j * 32) * K + k0, lB0 + j * 2048);
        __syncthreads();

#pragma unroll
        for (int h = 0; h < 2; h++) {
            const int slot = ((h * 4 + g) ^ xm) * 8;
            s16x8 af[4], bf[4];
#pragma unroll
            for (int mi = 0; mi < 4; mi++)
                af[mi] = *(const s16x8*)&As[(wr * 64 + mi * 16 + cc) * 64 + slot];
#pragma unroll
            for (int ni = 0; ni < 4; ni++)
                bf[ni] = *(const s16x8*)&Bs[(wc * 64 + ni * 16 + cc) * 64 + slot];
#pragma unroll
            for (int mi = 0; mi < 4; mi++)
#pragma unroll
                for (int ni = 0; ni < 4; ni++)
                    acc[mi][ni] = mfma_bf16(af[mi], bf[ni], acc[mi][ni]);
        }
        __syncthreads();
    }

#pragma unroll
    for (int ni = 0; ni < 4; ni++) {
        int col = col0 + wc * 64 + ni * 16 + cc;
        float bvv = 0.f;
        if (OUTMODE != 2) bvv = bias[col];
        if (OUTMODE == 3) {
            int head = col >> 6, dh = col & 63;
#pragma unroll
            for (int mi = 0; mi < 4; mi++) {
                int row = row0 + wr * 64 + mi * 16 + g * 4;     // s global
                int bb = row >> 11, sl = row & 2047;
                u16 us[4];
#pragma unroll
                for (int r = 0; r < 4; r++) us[r] = f2bf(acc[mi][ni][r] + bvv);
                *(uint2*)&((u16*)Cout)[(((size_t)(bb * 16 + head) * 64 + dh) << 11) + sl]
                    = *(uint2*)us;
            }
        } else {
#pragma unroll
            for (int mi = 0; mi < 4; mi++) {
                int row = row0 + wr * 64 + mi * 16 + g * 4;
#pragma unroll
                for (int r = 0; r < 4; r++) {
                    float v = acc[mi][ni][r] + bvv;
                    if (RELU) v = fmaxf(v, 0.f);
                    size_t idx = (size_t)(row + r) * N + col;
                    if (OUTMODE == 0) ((float*)Cout)[idx] = v;
                    else              ((u16*)Cout)[idx] = f2bf(v);
                }
            }
        }
    }
}

#define GEMM_LDS_DECL \
    __shared__ __align__(16) u16 As[128 * 64]; \
    __shared__ __align__(16) u16 Bs[128 * 64];

// Q, K, V projections in ONE launch: z=0 -> Q, z=1 -> K, z=2 -> V transposed into Vt.
__global__ __launch_bounds__(256, 4) void k_gemm_qkv(
    const u16* __restrict__ A, const u16* __restrict__ Wq, const u16* __restrict__ Wk,
    const u16* __restrict__ Wv, const float* __restrict__ bq, const float* __restrict__ bk,
    const float* __restrict__ bv, u16* __restrict__ Q, u16* __restrict__ K,
    u16* __restrict__ Vt, int M, int N, int Kd)
{
    GEMM_LDS_DECL
    int bx, by, bz; xcd_swz(bx, by, bz);
    if (bz == 0)
        gemm_body<0, 1>(As, Bs, A, Wq, bq, Q,  M, N, Kd, by * 128, bx * 128, 0, Kd);
    else if (bz == 1)
        gemm_body<0, 1>(As, Bs, A, Wk, bk, K,  M, N, Kd, by * 128, bx * 128, 0, Kd);
    else
        gemm_body<0, 3>(As, Bs, A, Wv, bv, Vt, M, N, Kd, by * 128, bx * 128, 0, Kd);
}

__global__ __launch_bounds__(256, 4) void k_gemm_relu_bf16(
    const u16* __restrict__ A, const u16* __restrict__ W, const float* __restrict__ bias,
    u16* __restrict__ C, int M, int N, int K)
{
    GEMM_LDS_DECL
    int bx, by, bz; xcd_swz(bx, by, bz);
    gemm_body<1, 1>(As, Bs, A, W, bias, C, M, N, K, by * 128, bx * 128, 0, K);
}

// FFN2 split-K partials: gridDim.z = 4, each covers K-range [bz*1024, +1024), bf16 out, no bias.
__global__ __launch_bounds__(256, 4) void k_gemm_part(
    const u16* __restrict__ A, const u16* __restrict__ W,
    u16* __restrict__ p0, u16* __restrict__ p1, u16* __restrict__ p2, u16* __restrict__ p3,
    int M, int N, int K)
{
    GEMM_LDS_DECL
    int bx, by, bz; xcd_swz(bx, by, bz);
    u16* out = (bz == 0) ? p0 : (bz == 1) ? p1 : (bz == 2) ? p2 : p3;
    gemm_body<0, 2>(As, Bs, A, W, nullptr, out, M, N, K, by * 128, bx * 128, bz * 1024, bz * 1024 + 1024);
}

// ---------------------------------------------------------------- flash attention
// R16-PROVEN: 512 thr (8 waves), KVB=128, swapped QK^T, fixed-shift softmax (shift in
// MFMA C-init), K dbuf with T4 counted-vmcnt, V reg-staged, bf16 out, XCD swizzle.
__global__ __launch_bounds__(512, 4) void k_flash(
    const u16* __restrict__ Q, const u16* __restrict__ Kb,
    const u16* __restrict__ Vt, u16* __restrict__ O)
{
    constexpr int S = 2048, Dm = 1024, H = 16;
    constexpr int KVB = 128, NT = S / KVB;
    constexpr float qsc = 0.125f * 1.44269504f;  // 1/sqrt(64) * log2(e)
    int bx, by, bz; xcd_swz(bx, by, bz);
    int qt = bx, h = by, b = bz;
    int tid = threadIdx.x, wid = tid >> 6, lane = tid & 63;
    int g = lane >> 4, cc = lane & 15;

    __shared__ __align__(16) u16 Ks[2][128 * 64];   // [kv][d], slot ^= (kv&7)
    __shared__ __align__(16) u16 Vs[64 * 128];      // [d][sigma(kv)], idx ^= (d&7)<<3

    int q0 = qt * 128 + wid * 16;
    size_t base = (size_t)b * S * Dm + h * 64;

    FragU uq0, uq1, qs0, qs1;
    uq0.s = *(const s16x8*)(Q + base + (size_t)(q0 + cc) * Dm + g * 8);
    uq1.s = *(const s16x8*)(Q + base + (size_t)(q0 + cc) * Dm + 32 + g * 8);
#pragma unroll
    for (int e = 0; e < 8; e++) {
        qs0.b[e] = (__bf16)((float)uq0.b[e] * qsc);
        qs1.b[e] = (__bf16)((float)uq1.b[e] * qsc);
    }
    s16x8 qf0 = qs0.s, qf1 = qs1.s;

    f32x4 minit = {-8.f, -8.f, -8.f, -8.f};   // fixed shift folded into C-init
    f32x4 zero = {0.f, 0.f, 0.f, 0.f};
    f32x4 o[4];
#pragma unroll
    for (int t = 0; t < 4; t++) o[t] = zero;
    f32x4 lacc = zero;                        // 4 independent l chains

    const int krow = tid >> 3;                         // 0..63
    const int kcol = ((tid & 7) ^ (krow & 7)) * 8;
    const u16* kSrcBase = Kb + base + (size_t)krow * Dm + kcol;
    const int kOff = wid * 512;                        // wave-uniform; HW adds lane*16B

    const int vrow = tid >> 3;                         // 0..63 (d)
    const int vch  = (tid & 7) * 8;                    // 0..56 (kv within tile)
    const int xmv  = (vrow & 7) << 3;
    const int cb0  = ((vch >> 5) << 5) | (((vch >> 4) & 1) << 2) | (((vch >> 2) & 3) << 3);
    const int cb1  = cb0 + 64;
    const u16* vSrcBase = Vt + (size_t)(b * H + h) * 64 * S + (size_t)vrow * S;
    u16* vq0a = &Vs[(vrow * 128 + cb0) ^ xmv];
    u16* vq0b = &Vs[(vrow * 128 + cb0 + 8) ^ xmv];
    u16* vq1a = &Vs[(vrow * 128 + cb1) ^ xmv];
    u16* vq1b = &Vs[(vrow * 128 + cb1 + 8) ^ xmv];

    const int xm = cc & 7;

    // prologue: K(0) gloads FIRST, then V(0) reg loads (VMEM order!)
    gload_lds16(kSrcBase,                   &Ks[0][kOff]);
    gload_lds16(kSrcBase + (size_t)64 * Dm, &Ks[0][kOff + 4096]);
    __builtin_amdgcn_sched_barrier(0);
    s16x8 vpre0 = *(const s16x8*)(vSrcBase + vch);
    s16x8 vpre1 = *(const s16x8*)(vSrcBase + 64 + vch);
    __builtin_amdgcn_sched_barrier(0);

    for (int it = 0; it < NT; ++it) {
        const int cur = it & 1;
        const int kv0 = it * KVB;

        asm volatile("s_waitcnt vmcnt(2)" ::: "memory");
        __builtin_amdgcn_s_barrier();
        __builtin_amdgcn_sched_barrier(0);

        {
            FragU a0, a1; a0.s = vpre0; a1.s = vpre1;
            *(uint2*)vq0a = make_uint2(a0.u.x, a0.u.y);
            *(uint2*)vq0b = make_uint2(a0.u.z, a0.u.w);
            *(uint2*)vq1a = make_uint2(a1.u.x, a1.u.y);
            *(uint2*)vq1b = make_uint2(a1.u.z, a1.u.w);
        }
        __builtin_amdgcn_sched_barrier(0);
        if (it + 1 < NT) {
            gload_lds16(kSrcBase + (size_t)(kv0 + KVB) * Dm,      &Ks[cur ^ 1][kOff]);
            gload_lds16(kSrcBase + (size_t)(kv0 + KVB + 64) * Dm, &Ks[cur ^ 1][kOff + 4096]);
        }
        __builtin_amdgcn_sched_barrier(0);
        asm volatile("s_waitcnt lgkmcnt(0)" ::: "memory");   // V ds_writes committed
        __builtin_amdgcn_s_barrier();
        __builtin_amdgcn_sched_barrier(0);

        const u16* Kc = Ks[cur];
        f32x4 sacc[8];
#pragma unroll
        for (int t = 0; t < 8; t++) sacc[t] = minit;
        __builtin_amdgcn_s_setprio(1);
#pragma unroll
        for (int t = 0; t < 8; t++) {
            const u16* kr = &Kc[(t * 16 + cc) * 64];
            s16x8 kf0 = *(const s16x8*)(kr + ((0 + g) ^ xm) * 8);
            s16x8 kf1 = *(const s16x8*)(kr + ((4 + g) ^ xm) * 8);
            sacc[t] = mfma_bf16(kf0, qf0, sacc[t]);
            sacc[t] = mfma_bf16(kf1, qf1, sacc[t]);
        }
        __builtin_amdgcn_s_setprio(0);

        FragU pb[4];
#pragma unroll
        for (int t = 0; t < 8; t++)
#pragma unroll
            for (int r = 0; r < 4; r++) {
                float pv = __builtin_amdgcn_exp2f(sacc[t][r]);
                lacc[r] += pv;
                pb[t >> 1].b[(t & 1) * 4 + r] = (__bf16)pv;
            }

        __builtin_amdgcn_s_setprio(1);
#pragma unroll
        for (int td = 0; td < 4; td++) {
            const int rb = (td * 16 + cc) * 128;
#pragma unroll
            for (int kk = 0; kk < 4; kk++) {
                s16x8 vf = *(const s16x8*)&Vs[(rb + kk * 32 + g * 8) ^ (xm << 3)];
                o[td] = mfma_bf16(vf, pb[kk].s, o[td]);
            }
        }
        __builtin_amdgcn_s_setprio(0);

        if (it + 1 < NT) {
            vpre0 = *(const s16x8*)(vSrcBase + kv0 + KVB + vch);
            vpre1 = *(const s16x8*)(vSrcBase + kv0 + KVB + 64 + vch);
        }
        __builtin_amdgcn_sched_barrier(0);
    }

    float l_run = (lacc[0] + lacc[1]) + (lacc[2] + lacc[3]);
    l_run += __shfl_xor(l_run, 16, 64);
    l_run += __shfl_xor(l_run, 32, 64);
    float inv = 1.f / l_run;
#pragma unroll
    for (int td = 0; td < 4; td++) {
        u16 us[4] = {f2bf(o[td][0] * inv), f2bf(o[td][1] * inv),
                     f2bf(o[td][2] * inv), f2bf(o[td][3] * inv)};
        *(uint2*)&O[(size_t)(b * S + q0 + cc) * Dm + h * 64 + td * 16 + g * 4] = *(uint2*)us;
    }
}

// ---------------------------------------------------------------- residual + LN1 -> bf16 h only
__global__ __launch_bounds__(256) void k_ln1(
    const float* __restrict__ A, const u16* __restrict__ B,
    const float* __restrict__ gw, const float* __restrict__ bw,
    u16* __restrict__ outb)
{
    constexpr int D = 1024;
    int row = blockIdx.x;
    int t = threadIdx.x;
    int lane = t & 63, wid = t >> 6;
    size_t idx = (size_t)row * D + t * 4;
    float4 va = ((const float4*)(A + (size_t)row * D))[t];
    uint2 vb = *(const uint2*)(B + idx);
    float v0 = va.x + bf2f((u16)vb.x);
    float v1 = va.y + bf2f((u16)(vb.x >> 16));
    float v2 = va.z + bf2f((u16)vb.y);
    float v3 = va.w + bf2f((u16)(vb.y >> 16));
    float sum = v0 + v1 + v2 + v3;
    float sq  = v0 * v0 + v1 * v1 + v2 * v2 + v3 * v3;
#pragma unroll
    for (int off = 1; off < 64; off <<= 1) {
        sum += __shfl_xor(sum, off, 64);
        sq  += __shfl_xor(sq,  off, 64);
    }
    __shared__ float s1[4], s2[4];
    if (lane == 0) { s1[wid] = sum; s2[wid] = sq; }
    __syncthreads();
    sum = s1[0] + s1[1] + s1[2] + s1[3];
    sq  = s2[0] + s2[1] + s2[2] + s2[3];
    float mu  = sum * (1.f / D);
    float var = sq * (1.f / D) - mu * mu;
    float rs  = rsqrtf(var + 1e-5f);
    float4 gv = ((const float4*)gw)[t];
    float4 bv = ((const float4*)bw)[t];
    u16 us[4] = {f2bf((v0 - mu) * rs * gv.x + bv.x),
                 f2bf((v1 - mu) * rs * gv.y + bv.y),
                 f2bf((v2 - mu) * rs * gv.z + bv.z),
                 f2bf((v3 - mu) * rs * gv.w + bv.w)};
    *(uint2*)(outb + idx) = *(uint2*)us;
}

// ---------------------------------------------------------------- LN2: h(bf16) + (p0..p3+bias) -> LN
__global__ __launch_bounds__(256) void k_ln2(
    const u16* __restrict__ A,
    const u16* __restrict__ p0, const u16* __restrict__ p1,
    const u16* __restrict__ p2, const u16* __restrict__ p3,
    const float* __restrict__ bias,
    const float* __restrict__ gw, const float* __restrict__ bw,
    float* __restrict__ outf)
{
    constexpr int D = 1024;
    int row = blockIdx.x;
    int t = threadIdx.x;
    int lane = t & 63, wid = t >> 6;
    size_t idx = (size_t)row * D + t * 4;
    uint2 ha = *(const uint2*)(A + idx);
    float4 bb = ((const float4*)bias)[t];
    float v0 = bf2f((u16)ha.x)         + bb.x;
    float v1 = bf2f((u16)(ha.x >> 16)) + bb.y;
    float v2 = bf2f((u16)ha.y)         + bb.z;
    float v3 = bf2f((u16)(ha.y >> 16)) + bb.w;
    const u16* ps[4] = {p0, p1, p2, p3};
#pragma unroll
    for (int pi = 0; pi < 4; pi++) {
        uint2 q = *(const uint2*)(ps[pi] + idx);
        v0 += bf2f((u16)q.x);
        v1 += bf2f((u16)(q.x >> 16));
        v2 += bf2f((u16)q.y);
        v3 += bf2f((u16)(q.y >> 16));
    }
    float sum = v0 + v1 + v2 + v3;
    float sq  = v0 * v0 + v1 * v1 + v2 * v2 + v3 * v3;
#pragma unroll
    for (int off = 1; off < 64; off <<= 1) {
        sum += __shfl_xor(sum, off, 64);
        sq  += __shfl_xor(sq,  off, 64);
    }
    __shared__ float s1[4], s2[4];
    if (lane == 0) { s1[wid] = sum; s2[wid] = sq; }
    __syncthreads();
    sum = s1[0] + s1[1] + s1[2] + s1[3];
    sq  = s2[0] + s2[1] + s2[2] + s2[3];
    float mu  = sum * (1.f / D);
    float var = sq * (1.f / D) - mu * mu;
    float rs  = rsqrtf(var + 1e-5f);
    float4 gv = ((const float4*)gw)[t];
    float4 bv = ((const float4*)bw)[t];
    float4 yo = {(v0 - mu) * rs * gv.x + bv.x,
                 (v1 - mu) * rs * gv.y + bv.y,
                 (v2 - mu) * rs * gv.z + bv.z,
                 (v3 - mu) * rs * gv.w + bv.w};
    ((float4*)(outf + (size_t)row * D))[t] = yo;
}

// ---------------------------------------------------------------- launch
extern "C" void kernel_launch(void* const* d_in, const int* in_sizes, int n_in,
                              void* d_out, int out_size, void* d_ws, size_t ws_size,
                              hipStream_t stream)
{
    constexpr int B = 2, S = 2048, D = 1024, F = 4096, H = 16;
    constexpr int M = B * S;
    const float* x   = (const float*)d_in[0];
    const float* Wq  = (const float*)d_in[1];
    const float* bq  = (const float*)d_in[2];
    const float* Wk  = (const float*)d_in[3];
    const float* bk  = (const float*)d_in[4];
    const float* Wv  = (const float*)d_in[5];
    const float* bv  = (const float*)d_in[6];
    const float* W1  = (const float*)d_in[7];
    const float* b1  = (const float*)d_in[8];
    const float* W2  = (const float*)d_in[9];
    const float* b2  = (const float*)d_in[10];
    const float* g1  = (const float*)d_in[11];
    const float* be1 = (const float*)d_in[12];
    const float* g2  = (const float*)d_in[13];
    const float* be2 = (const float*)d_in[14];
    float* out = (float*)d_out;

    char* ws = (char*)d_ws;
    size_t off = 0;
    auto alloc = [&](size_t bytes) {
        void* p = ws + off;
        off += (bytes + 255) & ~(size_t)255;
        return p;
    };
    u16* xb    = (u16*)alloc((size_t)M * D * 2);   // dead after QKV -> p0
    u16* wqb   = (u16*)alloc((size_t)D * D * 2);
    u16* wkb   = (u16*)alloc((size_t)D * D * 2);
    u16* wvb   = (u16*)alloc((size_t)D * D * 2);
    u16* w1b   = (u16*)alloc((size_t)F * D * 2);   // dead after FFN1 -> p1
    u16* w2b   = (u16*)alloc((size_t)D * F * 2);
    u16* Qb    = (u16*)alloc((size_t)M * D * 2);   // dead after flash -> p3
    u16* Kbf   = (u16*)alloc((size_t)M * D * 2);
    u16* Vtb   = (u16*)alloc((size_t)M * D * 2);
    u16* ffn1  = (u16*)alloc((size_t)M * F * 2);   // dedicated: must NOT alias p0..p3
    u16* attnb = (u16*)alloc((size_t)M * D * 2);   // bf16 attn; dead after LN1 -> p2
    u16* hb    = (u16*)alloc((size_t)M * D * 2);
    u16* p0 = xb;
    u16* p1 = w1b;
    u16* p2 = attnb;
    u16* p3 = Qb;

    dim3 blk(256);
    k_cast_all<<<dim3(128, 6), blk, 0, stream>>>(
        x,  xb,  M * D / 4,
        Wq, wqb, D * D / 4,
        Wk, wkb, D * D / 4,
        Wv, wvb, D * D / 4,
        W1, w1b, F * D / 4,
        W2, w2b, D * F / 4);

    k_gemm_qkv<<<dim3(D / 128, M / 128, 3), blk, 0, stream>>>(
        xb, wqb, wkb, wvb, bq, bk, bv, Qb, Kbf, Vtb, M, D, D);
    k_flash<<<dim3(S / 128, H, B), dim3(512), 0, stream>>>(Qb, Kbf, Vtb, attnb);
    k_ln1<<<dim3(M), blk, 0, stream>>>(x, attnb, g1, be1, hb);
    k_gemm_relu_bf16<<<dim3(F / 128, M / 128), blk, 0, stream>>>(hb, w1b, b1, ffn1, M, F, D);
    k_gemm_part<<<dim3(D / 128, M / 128, 4), blk, 0, stream>>>(
        ffn1, w2b, p0, p1, p2, p3, M, D, F);
    k_ln2<<<dim3(M), blk, 0, stream>>>(hb, p0, p1, p2, p3, b2, g2, be2, out);
}